// Round 6
// baseline (278.486 us; speedup 1.0000x reference)
//
#include <hip/hip_runtime.h>
#include <stdint.h>

// out[b,n] = sum_{c,hw} x[b,c,hw]*W_s[n,hw]*W_d[n,c] + W_b[n]
// GEMM: A = x (M=8192, K=3136), B = W_s (N=1024, K=3136), fused c-contraction.
// R16: R15 (LDS-free GEMM on pre-packed fragments) with the bias-init OOB
//      fixed: loop bound was M/C*N*8 = 262144 (8x the 32768-elem out buffer,
//      heap-corrupting device write -> abort). Bound is now 32768. No other
//      change -- R15's theory (GEMM was LDS-pipe-bound: 128 KB/tile/CU ~1500
//      cyc serialized with 1240 cyc MFMA) still needs its counter read.
//      Fragment order: frag(rb,kt)[lane] = T[rb*16+(lane&15)][kt*32+(lane>>4)*8..+8]
//      (identical to what the verified R10 LDS path fed the MFMA).

#define K_DIM 3136
#define N_DIM 1024
#define C_DIM 256
#define M_DIM 8192
#define X_ELEMS (M_DIM * K_DIM)   // 25690112 = 512 mb * 98 kt * 512
#define WS_ELEMS (N_DIM * K_DIM)  // 3211264  =  64 nb * 98 kt * 512
#define OUT_ELEMS (M_DIM / C_DIM * N_DIM)  // 32768
#define NKT 98                    // K-tiles of 32 over full K
#define NSTEP 49                  // K-tiles per split-K half
#define FSTR ((size_t)NKT * 512)  // shorts between row-block frags

typedef __attribute__((ext_vector_type(8))) short short8v;   // 8 bf16
typedef __attribute__((ext_vector_type(4))) float f32x4;

__device__ __forceinline__ short f2bf(float f) {
  union { float f; unsigned u; } v; v.f = f;
  unsigned r = v.u + 0x7FFFu + ((v.u >> 16) & 1u);
  return (short)(r >> 16);
}

// ---- convert + pack: fp32 [rows][3136] -> bf16 fragment order ----
// Tile: 64 rows x 64 k (one kt-pair) per block. Read coalesced (64B/lane),
// transpose through LDS, write frags coalesced (16B/lane, 512B bursts).
__global__ __launch_bounds__(256) void convert_pack(
    const float* __restrict__ x, const float* __restrict__ Ws,
    const float* __restrict__ Wb, short* __restrict__ Apk,
    short* __restrict__ Bpk, float* __restrict__ out) {
  const int ktp = blockIdx.x;   // 0..48 (kt-pair)
  const int yg = blockIdx.y;    // 0..127 A, 128..143 B, 144 bias
  const int t = threadIdx.x;

  if (yg == 144) {  // bias init: out[b,n] = W_b[n]  (OUT_ELEMS = 32768)
    for (int i = ktp * 256 + t; i < OUT_ELEMS; i += 49 * 256)
      out[i] = Wb[i & (N_DIM - 1)];
    return;
  }

  __shared__ short lds[64][72];  // +8 pad
  const float* src;
  short* dst;
  int rowbase;
  if (yg < 128) { src = x;  dst = Apk; rowbase = yg * 64; }
  else          { src = Ws; dst = Bpk; rowbase = (yg - 128) * 64; }

  // read: 4 threads/row, 64B each (16 fp32), fully coalesced per row.
  const int rr = t >> 2;
  const int cc = (t & 3) * 16;
  const float* in = src + (size_t)(rowbase + rr) * K_DIM + ktp * 64 + cc;
  f32x4 v0 = __builtin_nontemporal_load((const f32x4*)in);
  f32x4 v1 = __builtin_nontemporal_load((const f32x4*)in + 1);
  f32x4 v2 = __builtin_nontemporal_load((const f32x4*)in + 2);
  f32x4 v3 = __builtin_nontemporal_load((const f32x4*)in + 3);
  short8v s0, s1;
  s0[0] = f2bf(v0.x); s0[1] = f2bf(v0.y); s0[2] = f2bf(v0.z); s0[3] = f2bf(v0.w);
  s0[4] = f2bf(v1.x); s0[5] = f2bf(v1.y); s0[6] = f2bf(v1.z); s0[7] = f2bf(v1.w);
  s1[0] = f2bf(v2.x); s1[1] = f2bf(v2.y); s1[2] = f2bf(v2.z); s1[3] = f2bf(v2.w);
  s1[4] = f2bf(v3.x); s1[5] = f2bf(v3.y); s1[6] = f2bf(v3.z); s1[7] = f2bf(v3.w);
  *(short8v*)&lds[rr][cc] = s0;
  *(short8v*)&lds[rr][cc + 8] = s1;
  __syncthreads();

  // write: 8 frags (4 row-blocks x 2 kt). thread t -> frag f = t>>5,
  // lane slots l = (t&31) + 32s. frag[l] = T[rbl*16 + (l&15)][ktl*32 +
  // (l>>4)*8 ..+8]. Writes: 32 lanes x 16B = 512B contiguous per s.
  const int f = t >> 5, sub = t & 31;
  const int rbl = f >> 1, ktl = f & 1;
  const size_t fb =
      ((size_t)((rowbase >> 4) + rbl) * NKT + (ktp * 2 + ktl)) * 512;
#pragma unroll
  for (int s = 0; s < 2; ++s) {
    const int l = sub + 32 * s;
    short8v w = *(const short8v*)&lds[rbl * 16 + (l & 15)][ktl * 32 + (l >> 4) * 8];
    *(short8v*)(dst + fb + l * 8) = w;
  }
}

// ---- LDS-free GEMM on packed fragments ----
#define SB0() __builtin_amdgcn_sched_barrier(0)

#define NTL(P) __builtin_nontemporal_load((const short8v*)(P))

#define LOADF(KT) {                                                           \
    const short* ap_ = Ab + (size_t)(KT) * 512;                               \
    fa0 = NTL(ap_);            fa1 = NTL(ap_ + FSTR);                         \
    fa2 = NTL(ap_ + 2 * FSTR); fa3 = NTL(ap_ + 3 * FSTR);                     \
    fa4 = NTL(ap_ + 4 * FSTR); fa5 = NTL(ap_ + 5 * FSTR);                     \
    fa6 = NTL(ap_ + 6 * FSTR); fa7 = NTL(ap_ + 7 * FSTR);                     \
    const short* bp_ = Bb + (size_t)(KT) * 512;                               \
    fb0 = *(const short8v*)bp_;            fb1 = *(const short8v*)(bp_ + FSTR); \
    fb2 = *(const short8v*)(bp_ + 2 * FSTR); fb3 = *(const short8v*)(bp_ + 3 * FSTR); \
    SB0(); }

#define LOADG(KT) {                                                           \
    const short* ap_ = Ab + (size_t)(KT) * 512;                               \
    ga0 = NTL(ap_);            ga1 = NTL(ap_ + FSTR);                         \
    ga2 = NTL(ap_ + 2 * FSTR); ga3 = NTL(ap_ + 3 * FSTR);                     \
    ga4 = NTL(ap_ + 4 * FSTR); ga5 = NTL(ap_ + 5 * FSTR);                     \
    ga6 = NTL(ap_ + 6 * FSTR); ga7 = NTL(ap_ + 7 * FSTR);                     \
    const short* bp_ = Bb + (size_t)(KT) * 512;                               \
    gb0 = *(const short8v*)bp_;            gb1 = *(const short8v*)(bp_ + FSTR); \
    gb2 = *(const short8v*)(bp_ + 2 * FSTR); gb3 = *(const short8v*)(bp_ + 3 * FSTR); \
    SB0(); }

#define M16(A, B, C) __builtin_amdgcn_mfma_f32_16x16x32_bf16(A, B, C, 0, 0, 0)

#define MFROW(J, BV, A0, A1, A2, A3, A4, A5, A6, A7)                          \
  acc[0][J] = M16(A0, BV, acc[0][J]); acc[1][J] = M16(A1, BV, acc[1][J]);     \
  acc[2][J] = M16(A2, BV, acc[2][J]); acc[3][J] = M16(A3, BV, acc[3][J]);     \
  acc[4][J] = M16(A4, BV, acc[4][J]); acc[5][J] = M16(A5, BV, acc[5][J]);     \
  acc[6][J] = M16(A6, BV, acc[6][J]); acc[7][J] = M16(A7, BV, acc[7][J]);

#define MFMAF                                                                 \
  __builtin_amdgcn_s_setprio(1);                                              \
  MFROW(0, fb0, fa0, fa1, fa2, fa3, fa4, fa5, fa6, fa7)                       \
  MFROW(1, fb1, fa0, fa1, fa2, fa3, fa4, fa5, fa6, fa7)                       \
  MFROW(2, fb2, fa0, fa1, fa2, fa3, fa4, fa5, fa6, fa7)                       \
  MFROW(3, fb3, fa0, fa1, fa2, fa3, fa4, fa5, fa6, fa7)                       \
  __builtin_amdgcn_s_setprio(0);

#define MFMAG                                                                 \
  __builtin_amdgcn_s_setprio(1);                                              \
  MFROW(0, gb0, ga0, ga1, ga2, ga3, ga4, ga5, ga6, ga7)                       \
  MFROW(1, gb1, ga0, ga1, ga2, ga3, ga4, ga5, ga6, ga7)                       \
  MFROW(2, gb2, ga0, ga1, ga2, ga3, ga4, ga5, ga6, ga7)                       \
  MFROW(3, gb3, ga0, ga1, ga2, ga3, ga4, ga5, ga6, ga7)                       \
  __builtin_amdgcn_s_setprio(0);

__global__ __launch_bounds__(512, 2) void gemm_pk(
    const short* __restrict__ Apk, const short* __restrict__ Bpk,
    const float* __restrict__ Wd, float* __restrict__ out) {
  // xcd = bid&7 pins (nt, z): B-slice = 16 nb x 49 kt x 1KB = 784 KB,
  // L2-resident, reused by all 32 mt-blocks on the XCD. A streams (nt loads).
  const int bid = blockIdx.x;
  const int xcd = bid & 7;
  const int nt = xcd >> 1;
  const int z = xcd & 1;
  const int mt = bid >> 3;
  const int ktg0 = z * NSTEP;

  const int tid = threadIdx.x;
  const int lane = tid & 63;
  const int wv = tid >> 6;              // 0..7
  const int r = lane & 15;
  const int q = lane >> 4;
  const int wm = wv >> 2, wn = wv & 3;  // 2M x 4N wave grid, per-wave 128x64

  const short* Ab =
      Apk + ((size_t)(mt * 16 + wm * 8) * NKT + ktg0) * 512 + lane * 8;
  const short* Bb =
      Bpk + ((size_t)(nt * 16 + wn * 4) * NKT + ktg0) * 512 + lane * 8;

  f32x4 acc[8][4];
#pragma unroll
  for (int i = 0; i < 8; ++i)
#pragma unroll
    for (int j = 0; j < 4; ++j) acc[i][j] = (f32x4)0.0f;

  short8v fa0, fa1, fa2, fa3, fa4, fa5, fa6, fa7, fb0, fb1, fb2, fb3;
  short8v ga0, ga1, ga2, ga3, ga4, ga5, ga6, ga7, gb0, gb1, gb2, gb3;

  LOADF(0);
#pragma unroll 1
  for (int u = 0; u < 24; ++u) {
    LOADG(2 * u + 1);
    MFMAF;             // tile 2u (compiler waits f-regs; g's 12 in flight)
    LOADF(2 * u + 2);
    MFMAG;             // tile 2u+1
  }
  MFMAF;               // tile 48

  // epilogue: out[mt, n] += sum_c acc * W_d[n, c]; A rows = (b=mt, c).
  // C/D frag layout: col = lane&15 (n), row = q*4 + reg (c).
#pragma unroll
  for (int j = 0; j < 4; ++j) {
    const int n_g = nt * 256 + wn * 64 + 16 * j + r;
    float p = 0.0f;
#pragma unroll
    for (int i = 0; i < 8; ++i) {
      const int c_l = wm * 128 + 16 * i + 4 * q;
      const float4 wd = *(const float4*)(Wd + (size_t)n_g * C_DIM + c_l);
      p += acc[i][j].x * wd.x + acc[i][j].y * wd.y + acc[i][j].z * wd.z +
           acc[i][j].w * wd.w;
    }
    p += __shfl_xor(p, 16, 64);
    p += __shfl_xor(p, 32, 64);
    if (q == 0) atomicAdd(&out[(size_t)mt * N_DIM + n_g], p);
  }
}

extern "C" void kernel_launch(void* const* d_in, const int* in_sizes, int n_in,
                              void* d_out, int out_size, void* d_ws, size_t ws_size,
                              hipStream_t stream) {
  const float* x = (const float*)d_in[0];
  const float* Ws = (const float*)d_in[1];
  const float* Wd = (const float*)d_in[2];
  const float* Wb = (const float*)d_in[3];
  float* out = (float*)d_out;
  short* apk = (short*)d_ws;            // packed A frags [512 mb][98 kt][512]
  short* bpk = apk + X_ELEMS;           // packed B frags [64 nb][98 kt][512]

  convert_pack<<<dim3(49, 145), dim3(256), 0, stream>>>(x, Ws, Wb, apk, bpk, out);
  gemm_pk<<<dim3(256), dim3(512), 0, stream>>>(apk, bpk, Wd, out);
}

// Round 7
// 228.227 us; speedup vs baseline: 1.2202x; 1.2202x over previous
//
#include <hip/hip_runtime.h>
#include <stdint.h>

// out[b,n] = sum_{c,hw} x[b,c,hw]*W_s[n,hw]*W_d[n,c] + W_b[n]
// GEMM: A = x (M=8192, K=3136), B = W_s (N=1024, K=3136), fused c-contraction.
// R17: combine the two overlap mechanisms that R10..R14 traded against each
//      other: (a) 2 blocks/CU cross-block wave overlap (R10: 48KB LDS) and
//      (b) counted-vmcnt intra-block pipeline (R11+: needed 128KB -> 1
//      block/CU, losing (a); four-way tie explained). Geometry: 256x128
//      tile, BK=32, 8 waves (4Mx2N, per-wave 64x64, acc[4][4], ~116 VGPR),
//      3-slot LDS ring = 72KB -> 2 blocks/CU (144 <= 160KB). Stage T+2
//      during T (3 async16/thread), vmcnt(3) counted (T+1 resident, T+2 in
//      flight; drains only in the 2-tile tail), ONE raw s_barrier per tile
//      (LGKM0 pre-barrier = WAR fence; per-wave vmcnt + barrier = publish).
//      Staging/read swizzle byte-identical to the R11/R12-verified BK=32
//      layout. Grid 512 = 32mt x 8nt x 2z; bid&7 = nt pins each nt's full-K
//      B-slice (802 KB) L2-resident per XCD; lockstep mt sweep shares A in L3.

#define K_DIM 3136
#define N_DIM 1024
#define C_DIM 256
#define M_DIM 8192
#define X_ELEMS (M_DIM * K_DIM)   // 25690112
#define WS_ELEMS (N_DIM * K_DIM)  // 3211264
#define NSTEP 49                  // BK=32 tiles per split-K half
#define SLOT 24576                // 16 KB A + 8 KB B
#define LDS_BYTES (3 * SLOT)      // 73728

typedef __attribute__((ext_vector_type(8))) short short8v;  // 8 bf16
typedef __attribute__((ext_vector_type(4))) float f32x4;

__device__ __forceinline__ short f2bf(float f) {
  union { float f; unsigned u; } v; v.f = f;
  unsigned r = v.u + 0x7FFFu + ((v.u >> 16) & 1u);
  return (short)(r >> 16);
}

// 16B-per-lane async global->LDS. LDS dest = wave-uniform base + lane*16.
__device__ __forceinline__ void async16(const void* g, void* l) {
  __builtin_amdgcn_global_load_lds(
      (const __attribute__((address_space(1))) unsigned int*)g,
      (__attribute__((address_space(3))) unsigned int*)l, 16, 0, 0);
}

// fp32 -> bf16 for x and W_s (16 elems/thread), plus bias into out.
#define XBLK (X_ELEMS / 4096)                 // 6272
#define CVBLK ((X_ELEMS + WS_ELEMS) / 4096)   // 7056
__global__ __launch_bounds__(256) void convert_bf16_bias(
    const float* __restrict__ x, const float* __restrict__ Ws,
    const float* __restrict__ Wb, short* __restrict__ dst,
    float* __restrict__ out) {
  int bid = blockIdx.x;
  if (bid >= CVBLK) {  // bias: 32768 out elems / 256 = 128 blocks
    int i = (bid - CVBLK) * 256 + threadIdx.x;
    out[i] = Wb[i & (N_DIM - 1)];
    return;
  }
  const float* src;
  short* d;
  size_t base;
  if (bid < XBLK) {
    src = x; d = dst; base = (size_t)bid * 4096;
  } else {
    src = Ws; d = dst + X_ELEMS; base = (size_t)(bid - XBLK) * 4096;
  }
#pragma unroll
  for (int h = 0; h < 2; ++h) {
    size_t i = base + threadIdx.x * 8 + h * 2048;
    f32x4 v0 = __builtin_nontemporal_load((const f32x4*)(src + i));
    f32x4 v1 = __builtin_nontemporal_load((const f32x4*)(src + i) + 1);
    short8v s;
    s[0] = f2bf(v0.x); s[1] = f2bf(v0.y); s[2] = f2bf(v0.z); s[3] = f2bf(v0.w);
    s[4] = f2bf(v1.x); s[5] = f2bf(v1.y); s[6] = f2bf(v1.z); s[7] = f2bf(v1.w);
    *(short8v*)(d + i) = s;
  }
}

// ---- GEMM: 3-slot counted-vmcnt ring, 2 blocks/CU ----
// LDS slot s (0..2) at byte s*24576: A[256 rows][32 bf16] then B[128][32] at
// +16384. Row = 64 B = 4 chunks of 16 B; slot chunk cs at row holds global
// chunk cs ^ ((row>>1)&3) (DMA-linear dest, pre-swizzled global source);
// reads XOR back. Conflict-free b128 (8 words/bank uniform; R11/R12 PMC 0).

#define VMCNT(N) asm volatile("s_waitcnt vmcnt(" #N ")" ::: "memory")
#define LGKM0() asm volatile("s_waitcnt lgkmcnt(0)" ::: "memory")
#define SB0() __builtin_amdgcn_sched_barrier(0)
#define CBAR() asm volatile("" ::: "memory")
#define BARR() { CBAR(); __builtin_amdgcn_s_barrier(); CBAR(); }

#define STAGE(T, SO) {                                                        \
    char* d_ = sm + (SO) + (wv << 10);                                        \
    const short* ga_ = Ag + (size_t)(T) * 32;                                 \
    async16(ga_, d_);                                                         \
    async16(ga_ + (size_t)128 * K_DIM, d_ + 8192);                            \
    async16(Bg + (size_t)(T) * 32, d_ + 16384); }

#define M16(A, B, C) __builtin_amdgcn_mfma_f32_16x16x32_bf16(A, B, C, 0, 0, 0)

// one K-tile body: 8 ds_read_b128 + 16 MFMA from slot at byte offset CO.
#define KBODY(CO)                                                             \
  {                                                                           \
    const char* sl = sm + (CO);                                               \
    short8v a0 = *(const short8v*)(sl + aoff);                                \
    short8v a1 = *(const short8v*)(sl + aoff + 1024);                         \
    short8v a2 = *(const short8v*)(sl + aoff + 2048);                         \
    short8v a3 = *(const short8v*)(sl + aoff + 3072);                         \
    short8v b0 = *(const short8v*)(sl + boff);                                \
    short8v b1 = *(const short8v*)(sl + boff + 1024);                         \
    short8v b2 = *(const short8v*)(sl + boff + 2048);                         \
    short8v b3 = *(const short8v*)(sl + boff + 3072);                         \
    SB0();                                                                    \
    __builtin_amdgcn_s_setprio(1);                                            \
    acc[0][0]=M16(a0,b0,acc[0][0]); acc[1][0]=M16(a1,b0,acc[1][0]);           \
    acc[2][0]=M16(a2,b0,acc[2][0]); acc[3][0]=M16(a3,b0,acc[3][0]);           \
    acc[0][1]=M16(a0,b1,acc[0][1]); acc[1][1]=M16(a1,b1,acc[1][1]);           \
    acc[2][1]=M16(a2,b1,acc[2][1]); acc[3][1]=M16(a3,b1,acc[3][1]);           \
    acc[0][2]=M16(a0,b2,acc[0][2]); acc[1][2]=M16(a1,b2,acc[1][2]);           \
    acc[2][2]=M16(a2,b2,acc[2][2]); acc[3][2]=M16(a3,b2,acc[3][2]);           \
    acc[0][3]=M16(a0,b3,acc[0][3]); acc[1][3]=M16(a1,b3,acc[1][3]);           \
    acc[2][3]=M16(a2,b3,acc[2][3]); acc[3][3]=M16(a3,b3,acc[3][3]);           \
    __builtin_amdgcn_s_setprio(0);                                            \
  }

__global__ __launch_bounds__(512, 4) void gemm_fused(
    const short* __restrict__ Abf, const short* __restrict__ Bbf,
    const float* __restrict__ Wd, float* __restrict__ out) {
  __shared__ __align__(16) char sm[LDS_BYTES];  // 72 KiB: 3-slot ring

  const int bid = blockIdx.x;
  const int nt = bid & 7;           // bid&7 -> XCD: B-slice pinned to L2
  const int mt = (bid >> 3) & 31;   // lockstep mt sweep across XCDs (L3 share)
  const int z = bid >> 8;           // split-K half: 49 + 49 tiles
  const int kt0 = z * NSTEP;

  const int tid = threadIdx.x;
  const int lane = tid & 63;
  const int wv = tid >> 6;              // 0..7
  const int r = lane & 15;
  const int q = lane >> 4;
  const int wm = wv >> 1, wn = wv & 1;  // 4M x 2N wave grid, per-wave 64x64

  // staging: row = wv*16 + (lane>>2) (+128 for A's 2nd async16), slot chunk
  // cs = lane&3 holds global chunk cs ^ ((row>>1)&3) = cs ^ ((lane>>3)&3).
  const int srow = wv * 16 + (lane >> 2);
  const int sk8 = (lane & 3) ^ ((lane >> 3) & 3);
  const short* Ag = Abf + (size_t)(mt * 256 + srow) * K_DIM + kt0 * 32 + sk8 * 8;
  const short* Bg = Bbf + (size_t)(nt * 128 + srow) * K_DIM + kt0 * 32 + sk8 * 8;

  // fragment reads: A row = wm*64 + i*16 + r, k-chunk q; swizzled chunk =
  // q ^ ((r>>1)&3) (row offsets are multiples of 16 -> swizzle term = r's).
  const int swz = (q ^ ((r >> 1) & 3)) << 4;
  const int aoff = (wm * 64 + r) * 64 + swz;
  const int boff = 16384 + (wn * 64 + r) * 64 + swz;

  f32x4 acc[4][4];
#pragma unroll
  for (int i = 0; i < 4; ++i)
#pragma unroll
    for (int j = 0; j < 4; ++j) acc[i][j] = (f32x4)0.0f;

  // prologue: stage tiles 0,1 (slots 0,1; 6 loads); wait tile 0 (3 in
  // flight); barrier publishes slot 0.
  STAGE(0, 0) STAGE(1, SLOT)
  VMCNT(3);
  BARR();

  unsigned co = 0, so = 2 * SLOT;
#pragma unroll 1
  for (int t = 0; t < NSTEP - 2; ++t) {
    STAGE(t + 2, so)
    KBODY(co)
    VMCNT(3);   // t+1 resident; t+2's 3 stay in flight
    LGKM0();    // my reads of slot t done -> safe to overwrite next iter
    BARR();     // publish t+1 + WAR rendezvous
    co += SLOT; if (co == LDS_BYTES) co = 0;
    so += SLOT; if (so == LDS_BYTES) so = 0;
  }
  // t = 47: no stage; final drain for tile 48.
  KBODY(co)
  VMCNT(0);
  BARR();
  co += SLOT; if (co == LDS_BYTES) co = 0;
  // t = 48: compute only.
  KBODY(co)

  // epilogue: out[mt, n] += sum_c acc * W_d[n, c]; A-tile = image mt, c = row.
  // C/D frag layout: col = lane&15 (n), row = q*4 + reg (c).
#pragma unroll
  for (int j = 0; j < 4; ++j) {
    const int n_g = nt * 128 + wn * 64 + 16 * j + r;
    float p = 0.0f;
#pragma unroll
    for (int i = 0; i < 4; ++i) {
      const int c_l = wm * 64 + 16 * i + 4 * q;
      const float4 wd = *(const float4*)(Wd + (size_t)n_g * C_DIM + c_l);
      p += acc[i][j].x * wd.x + acc[i][j].y * wd.y + acc[i][j].z * wd.z +
           acc[i][j].w * wd.w;
    }
    p += __shfl_xor(p, 16, 64);
    p += __shfl_xor(p, 32, 64);
    if (q == 0) atomicAdd(&out[(size_t)mt * N_DIM + n_g], p);
  }
}

extern "C" void kernel_launch(void* const* d_in, const int* in_sizes, int n_in,
                              void* d_out, int out_size, void* d_ws, size_t ws_size,
                              hipStream_t stream) {
  const float* x = (const float*)d_in[0];
  const float* Ws = (const float*)d_in[1];
  const float* Wd = (const float*)d_in[2];
  const float* Wb = (const float*)d_in[3];
  float* out = (float*)d_out;
  short* xbf = (short*)d_ws;  // [X_ELEMS] bf16 x, then [WS_ELEMS] bf16 W_s

  convert_bf16_bias<<<dim3(CVBLK + 128), dim3(256), 0, stream>>>(x, Ws, Wb, xbf, out);
  gemm_fused<<<dim3(512), dim3(512), 0, stream>>>(xbf, xbf + X_ELEMS, Wd, out);
}